// Round 15
// baseline (287.165 us; speedup 1.0000x reference)
//
#include <hip/hip_runtime.h>
#include <math.h>

#define CH 256
#define SCAN_BLOCK 1024
#define LOG2E 1.44269504088896f

typedef _Float16 h2 __attribute__((ext_vector_type(2)));
typedef _Float16 h4 __attribute__((ext_vector_type(4)));
typedef _Float16 f16x8 __attribute__((ext_vector_type(8)));
typedef float f32x4 __attribute__((ext_vector_type(4)));

__device__ __forceinline__ float elu(float v)   { return v > 0.f ? v : __expf(v) - 1.f; }

__device__ __forceinline__ unsigned short f2h(float f) {
    union { _Float16 h; unsigned short u; } c;
    c.h = (_Float16)f;
    return c.u;
}

// packed-f16 edge logit: dot(att, lrelu(r + xr)) over this lane's 4 channels
__device__ __forceinline__ float edge_logit(h4 r, h2 xrlo, h2 xrhi, h2 alo, h2 ahi) {
    const h2 k = {(_Float16)0.2f, (_Float16)0.2f};
    h2 rlo = {r.x, r.y}, rhi = {r.z, r.w};
    h2 slo = rlo + xrlo;
    h2 shi = rhi + xrhi;
    slo = __builtin_elementwise_max(slo, slo * k);   // v_pk_max_f16 (lrelu)
    shi = __builtin_elementwise_max(shi, shi * k);
    float p = __builtin_amdgcn_fdot2(slo, alo, 0.f, false);   // v_dot2_f32_f16
    return __builtin_amdgcn_fdot2(shi, ahi, p, false);
}

// DPP butterfly add steps (VALU cross-lane, no DS pipe)
template<int C>
__device__ __forceinline__ float dppadd(float v) {
    int t = __builtin_amdgcn_update_dpp(0, __float_as_int(v), C, 0xf, 0xf, true);
    return v + __int_as_float(t);
}
// reduce within each 16-lane group: xor1,xor2 (quad_perm), xor4 (half_mirror), xor8 (mirror)
__device__ __forceinline__ float red16(float p) {
    p = dppadd<0xB1>(p);    // quad_perm [1,0,3,2]
    p = dppadd<0x4E>(p);    // quad_perm [2,3,0,1]
    p = dppadd<0x141>(p);   // row_half_mirror
    p = dppadd<0x140>(p);   // row_mirror
    return p;
}
// full 64-lane reduce: DPP within 16, then cross-row via shuffle (verified R6 structure)
__device__ __forceinline__ float red64(float p) {
    p = red16(p);
    p += __shfl_xor(p, 16);
    p += __shfl_xor(p, 32);
    return p;
}

// async global->LDS, 16B per lane, wave-uniform LDS base (dest = base + lane*16)
typedef const __attribute__((address_space(1))) unsigned int* gas_p;
typedef __attribute__((address_space(3))) unsigned int* las_p;
__device__ __forceinline__ void gload16(const unsigned short* g, unsigned short* l) {
    __builtin_amdgcn_global_load_lds((gas_p)g, (las_p)l, 16, 0, 0);
}

// ---------------- GEMM1: x (n x 20) @ W (20 x 256) + b -> f16 xl, xr ----------------
__global__ __launch_bounds__(256) void gemm1_kernel(const float* __restrict__ x,
                             const float* __restrict__ Wl, const float* __restrict__ bl,
                             const float* __restrict__ Wr, const float* __restrict__ br,
                             unsigned short* __restrict__ xl, unsigned short* __restrict__ xr, int n) {
    __shared__ float xs[64][20];
    int n0 = blockIdx.x * 64;
    int tid = threadIdx.x;
    for (int i = tid; i < 64 * 20; i += 256) {
        int m = i / 20, k = i % 20;
        int row = n0 + m;
        xs[m][k] = (row < n) ? x[(size_t)row * 20 + k] : 0.f;
    }
    int c = tid;
    float wl[20], wr[20];
#pragma unroll
    for (int k = 0; k < 20; ++k) { wl[k] = Wl[k * 256 + c]; wr[k] = Wr[k * 256 + c]; }
    float blv = bl[c], brv = br[c];
    __syncthreads();
#pragma unroll 1
    for (int g = 0; g < 8; ++g) {
        int base = g * 8;
        float al[8], ar[8];
#pragma unroll
        for (int m = 0; m < 8; ++m) { al[m] = blv; ar[m] = brv; }
#pragma unroll
        for (int k = 0; k < 20; ++k) {
            float wlv = wl[k], wrv = wr[k];
#pragma unroll
            for (int m = 0; m < 8; ++m) {
                float xv = xs[base + m][k];
                al[m] += xv * wlv;
                ar[m] += xv * wrv;
            }
        }
#pragma unroll
        for (int m = 0; m < 8; ++m) {
            int row = n0 + base + m;
            if (row < n) {
                xl[(size_t)row * 256 + c] = f2h(al[m]);
                xr[(size_t)row * 256 + c] = f2h(ar[m]);
            }
        }
    }
}

// ---------------- CSR build ----------------
__global__ void count_deg(const int* __restrict__ ei, int* __restrict__ deg, int e) {
    int t = blockIdx.x * blockDim.x + threadIdx.x;
    if (t < e) atomicAdd(&deg[ei[e + t]], 1);
}

__global__ void scan_block_k(const int* __restrict__ deg, int* __restrict__ rowptr,
                             int* __restrict__ bsums, int n) {
    __shared__ int wsum[16];
    __shared__ int woff[17];
    int tid = threadIdx.x;
    int gi = blockIdx.x * SCAN_BLOCK + tid;
    int lane = tid & 63, wid = tid >> 6;
    int v = (gi < n) ? deg[gi] : 0;
    int incl = v;
#pragma unroll
    for (int d = 1; d < 64; d <<= 1) {
        int t = __shfl_up(incl, d, 64);
        if (lane >= d) incl += t;
    }
    if (lane == 63) wsum[wid] = incl;
    __syncthreads();
    if (tid < 16) {
        int s = wsum[tid];
#pragma unroll
        for (int d = 1; d < 16; d <<= 1) {
            int t = __shfl_up(s, d, 64);
            if (tid >= d) s += t;
        }
        woff[tid + 1] = s;
        if (tid == 0) woff[0] = 0;
    }
    __syncthreads();
    incl += woff[wid];
    if (gi < n) rowptr[gi + 1] = incl;
    if (tid == 0) bsums[blockIdx.x] = woff[16];
}

__global__ void scan_tops_k(int* bsums, int nb) {
    int tid = threadIdx.x;
    int v = (tid < nb) ? bsums[tid] : 0;
    int incl = v;
#pragma unroll
    for (int d = 1; d < 64; d <<= 1) {
        int t = __shfl_up(incl, d, 64);
        if (tid >= d) incl += t;
    }
    if (tid < nb) bsums[tid] = incl - v;
}

__global__ void scan_fix_k(int* __restrict__ rowptr, int* __restrict__ cursor,
                           const int* __restrict__ deg, const int* __restrict__ bsums, int n) {
    int gi = blockIdx.x * SCAN_BLOCK + threadIdx.x;
    if (gi >= n) return;
    int off = bsums[blockIdx.x];
    int incl = rowptr[gi + 1] + off;
    rowptr[gi + 1] = incl;
    cursor[gi] = incl - deg[gi];
    if (gi == 0) rowptr[0] = 0;
}

__global__ void scatter_k(const int* __restrict__ ei, int* __restrict__ cursor,
                          int* __restrict__ csr, int e) {
    int t = blockIdx.x * blockDim.x + threadIdx.x;
    if (t >= e) return;
    int s = ei[t], d = ei[e + t];
    int idx = atomicAdd(&cursor[d], 1);
    csr[idx] = s;
}

// ---- Fused GATv2 layer 1 (f16 in, f16 out): no-max softmax, depth-2 quad pipeline ----
__global__ void fused_gat1(const unsigned short* __restrict__ xl, const unsigned short* __restrict__ xr,
                           const int* __restrict__ rowptr, const int* __restrict__ csr,
                           const float* __restrict__ att, const float* __restrict__ bias,
                           unsigned short* __restrict__ hout, int n) {
    int wid = threadIdx.x >> 6;
    int lane = threadIdx.x & 63;
    int i = blockIdx.x * 4 + wid;
    if (i >= n) return;
    h4 xr4 = ((const h4*)(xr + (size_t)i * CH))[lane];
    h2 xrlo = {xr4.x, xr4.y}, xrhi = {xr4.z, xr4.w};
    float4 a4 = ((const float4*)att)[lane];
    h2 alo = {(_Float16)(a4.x * LOG2E), (_Float16)(a4.y * LOG2E)};
    h2 ahi = {(_Float16)(a4.z * LOG2E), (_Float16)(a4.w * LOG2E)};
    h4 xli = ((const h4*)(xl + (size_t)i * CH))[lane];
    int beg = rowptr[i], end = rowptr[i + 1];
    int el = end - 1;
    // preload two quads (8 rows in flight) BEFORE the self-loop compute
    h4 A0, A1, A2, A3, B0, B1, B2, B3;
    int e0 = beg;
    if (e0 < end) {
        int s0 = csr[e0], s1 = csr[min(e0 + 1, el)], s2 = csr[min(e0 + 2, el)], s3 = csr[min(e0 + 3, el)];
        A0 = ((const h4*)(xl + (size_t)s0 * CH))[lane];
        A1 = ((const h4*)(xl + (size_t)s1 * CH))[lane];
        A2 = ((const h4*)(xl + (size_t)s2 * CH))[lane];
        A3 = ((const h4*)(xl + (size_t)s3 * CH))[lane];
        e0 += 4;
    }
    if (e0 < end) {
        int s0 = csr[e0], s1 = csr[min(e0 + 1, el)], s2 = csr[min(e0 + 2, el)], s3 = csr[min(e0 + 3, el)];
        B0 = ((const h4*)(xl + (size_t)s0 * CH))[lane];
        B1 = ((const h4*)(xl + (size_t)s1 * CH))[lane];
        B2 = ((const h4*)(xl + (size_t)s2 * CH))[lane];
        B3 = ((const h4*)(xl + (size_t)s3 * CH))[lane];
        e0 += 4;
    }
    // self-loop (overlaps with in-flight gathers)
    float ws = __builtin_exp2f(red16(edge_logit(xli, xrlo, xrhi, alo, ahi)));
    float l = ws;
    float4 acc = make_float4(ws * (float)xli.x, ws * (float)xli.y,
                             ws * (float)xli.z, ws * (float)xli.w);

#define GAT1_COMPUTE(Q0, Q1, Q2, Q3, eg)  do {                                   \
        int cnt = end - (eg);                                                    \
        float p0 = red16(edge_logit(Q0, xrlo, xrhi, alo, ahi));                  \
        float p1 = red16(edge_logit(Q1, xrlo, xrhi, alo, ahi));                  \
        float p2 = red16(edge_logit(Q2, xrlo, xrhi, alo, ahi));                  \
        float p3 = red16(edge_logit(Q3, xrlo, xrhi, alo, ahi));                  \
        if (cnt < 2) p1 = -INFINITY;                                             \
        if (cnt < 3) p2 = -INFINITY;                                             \
        if (cnt < 4) p3 = -INFINITY;                                             \
        float w0 = __builtin_exp2f(p0), w1 = __builtin_exp2f(p1);                \
        float w2 = __builtin_exp2f(p2), w3 = __builtin_exp2f(p3);                \
        l += (w0 + w1) + (w2 + w3);                                              \
        acc.x += w0*(float)Q0.x + w1*(float)Q1.x + w2*(float)Q2.x + w3*(float)Q3.x; \
        acc.y += w0*(float)Q0.y + w1*(float)Q1.y + w2*(float)Q2.y + w3*(float)Q3.y; \
        acc.z += w0*(float)Q0.z + w1*(float)Q1.z + w2*(float)Q2.z + w3*(float)Q3.z; \
        acc.w += w0*(float)Q0.w + w1*(float)Q1.w + w2*(float)Q2.w + w3*(float)Q3.w; \
    } while (0)

#define GAT_REFILL(Q0, Q1, Q2, Q3)  do {                                         \
        if (e0 < end) {                                                          \
            int s0 = csr[e0], s1 = csr[min(e0 + 1, el)];                         \
            int s2 = csr[min(e0 + 2, el)], s3 = csr[min(e0 + 3, el)];            \
            Q0 = ((const h4*)(xl + (size_t)s0 * CH))[lane];                      \
            Q1 = ((const h4*)(xl + (size_t)s1 * CH))[lane];                      \
            Q2 = ((const h4*)(xl + (size_t)s2 * CH))[lane];                      \
            Q3 = ((const h4*)(xl + (size_t)s3 * CH))[lane];                      \
            e0 += 4;                                                             \
        }                                                                        \
    } while (0)

    int e = beg;
    while (e < end) {
        GAT1_COMPUTE(A0, A1, A2, A3, e);
        e += 4;
        if (e >= end) break;
        GAT_REFILL(A0, A1, A2, A3);
        GAT1_COMPUTE(B0, B1, B2, B3, e);
        e += 4;
        if (e >= end) break;
        GAT_REFILL(B0, B1, B2, B3);
    }
#undef GAT1_COMPUTE

    float inv = 1.f / l;
    float4 b4 = ((const float4*)bias)[lane];
    h4 o;
    o.x = (_Float16)elu(acc.x * inv + b4.x);
    o.y = (_Float16)elu(acc.y * inv + b4.y);
    o.z = (_Float16)elu(acc.z * inv + b4.z);
    o.w = (_Float16)elu(acc.w * inv + b4.w);
    ((h4*)(hout + (size_t)i * CH))[lane] = o;
}

// ---- Fused GATv2 layer 2 (f16 in, fp32 out): same structure, 64-lane reduce ----
__global__ void fused_gat2(const unsigned short* __restrict__ xl, const unsigned short* __restrict__ xr,
                           const int* __restrict__ rowptr, const int* __restrict__ csr,
                           const float* __restrict__ att, const float* __restrict__ bias,
                           float* __restrict__ out, int n) {
    int wid = threadIdx.x >> 6;
    int lane = threadIdx.x & 63;
    int i = blockIdx.x * 4 + wid;
    if (i >= n) return;
    h4 xr4 = ((const h4*)(xr + (size_t)i * CH))[lane];
    h2 xrlo = {xr4.x, xr4.y}, xrhi = {xr4.z, xr4.w};
    float4 a4 = ((const float4*)att)[lane];
    h2 alo = {(_Float16)(a4.x * LOG2E), (_Float16)(a4.y * LOG2E)};
    h2 ahi = {(_Float16)(a4.z * LOG2E), (_Float16)(a4.w * LOG2E)};
    h4 xli = ((const h4*)(xl + (size_t)i * CH))[lane];
    int beg = rowptr[i], end = rowptr[i + 1];
    int el = end - 1;
    h4 A0, A1, A2, A3, B0, B1, B2, B3;
    int e0 = beg;
    if (e0 < end) {
        int s0 = csr[e0], s1 = csr[min(e0 + 1, el)], s2 = csr[min(e0 + 2, el)], s3 = csr[min(e0 + 3, el)];
        A0 = ((const h4*)(xl + (size_t)s0 * CH))[lane];
        A1 = ((const h4*)(xl + (size_t)s1 * CH))[lane];
        A2 = ((const h4*)(xl + (size_t)s2 * CH))[lane];
        A3 = ((const h4*)(xl + (size_t)s3 * CH))[lane];
        e0 += 4;
    }
    if (e0 < end) {
        int s0 = csr[e0], s1 = csr[min(e0 + 1, el)], s2 = csr[min(e0 + 2, el)], s3 = csr[min(e0 + 3, el)];
        B0 = ((const h4*)(xl + (size_t)s0 * CH))[lane];
        B1 = ((const h4*)(xl + (size_t)s1 * CH))[lane];
        B2 = ((const h4*)(xl + (size_t)s2 * CH))[lane];
        B3 = ((const h4*)(xl + (size_t)s3 * CH))[lane];
        e0 += 4;
    }
    float ws = __builtin_exp2f(red64(edge_logit(xli, xrlo, xrhi, alo, ahi)));
    float l = ws;
    float4 acc = make_float4(ws * (float)xli.x, ws * (float)xli.y,
                             ws * (float)xli.z, ws * (float)xli.w);

#define GAT2_COMPUTE(Q0, Q1, Q2, Q3, eg)  do {                                   \
        int cnt = end - (eg);                                                    \
        float p0 = red64(edge_logit(Q0, xrlo, xrhi, alo, ahi));                  \
        float p1 = red64(edge_logit(Q1, xrlo, xrhi, alo, ahi));                  \
        float p2 = red64(edge_logit(Q2, xrlo, xrhi, alo, ahi));                  \
        float p3 = red64(edge_logit(Q3, xrlo, xrhi, alo, ahi));                  \
        if (cnt < 2) p1 = -INFINITY;                                             \
        if (cnt < 3) p2 = -INFINITY;                                             \
        if (cnt < 4) p3 = -INFINITY;                                             \
        float w0 = __builtin_exp2f(p0), w1 = __builtin_exp2f(p1);                \
        float w2 = __builtin_exp2f(p2), w3 = __builtin_exp2f(p3);                \
        l += (w0 + w1) + (w2 + w3);                                              \
        acc.x += w0*(float)Q0.x + w1*(float)Q1.x + w2*(float)Q2.x + w3*(float)Q3.x; \
        acc.y += w0*(float)Q0.y + w1*(float)Q1.y + w2*(float)Q2.y + w3*(float)Q3.y; \
        acc.z += w0*(float)Q0.z + w1*(float)Q1.z + w2*(float)Q2.z + w3*(float)Q3.z; \
        acc.w += w0*(float)Q0.w + w1*(float)Q1.w + w2*(float)Q2.w + w3*(float)Q3.w; \
    } while (0)

    int e = beg;
    while (e < end) {
        GAT2_COMPUTE(A0, A1, A2, A3, e);
        e += 4;
        if (e >= end) break;
        GAT_REFILL(A0, A1, A2, A3);
        GAT2_COMPUTE(B0, B1, B2, B3, e);
        e += 4;
        if (e >= end) break;
        GAT_REFILL(B0, B1, B2, B3);
    }
#undef GAT2_COMPUTE
#undef GAT_REFILL

    float inv = 1.f / l;
    float4 b4 = ((const float4*)bias)[lane];
    float4 o;
    o.x = acc.x * inv + b4.x;
    o.y = acc.y * inv + b4.y;
    o.z = acc.z * inv + b4.z;
    o.w = acc.w * inv + b4.w;
    ((float4*)(out + (size_t)i * CH))[lane] = o;
}

// ---------------- transpose+convert layer2 weights: Wt[z][n][k] f16 ----------------
__global__ void wconv(const float* __restrict__ Wl2, const float* __restrict__ Wr2,
                      unsigned short* __restrict__ Wt) {
    int t = blockIdx.x * 256 + threadIdx.x;
    int z = t >> 16;
    int idx = t & 65535;
    int k = idx >> 8, nn = idx & 255;
    const float* W = z ? Wr2 : Wl2;
    Wt[z * 65536 + nn * 256 + k] = f2h(W[k * 256 + nn]);
}

// ---------------- GEMM2 MFMA: h (M x 256 f16) @ {Wl2,Wr2}^T + b, BOTH z per block ----
// v6: z-merged. Each block stages its A-tile ONCE plus both weight tiles (B0, B1) and
// runs 32 MFMAs per barrier (2x amortization of the barrier/drain cost that dominates
// at MfmaUtil 8%), halving A's global traffic. Staging/fragment/epilogue patterns are
// the R13-verified ones. XCD swizzle keeps the two A-sharing (by) blocks on one XCD.
#define LDE 32
__global__ __launch_bounds__(256) void gemm_mfma(
        const unsigned short* __restrict__ A,
        const unsigned short* __restrict__ Wt,
        const float* __restrict__ ba, const float* __restrict__ bb,
        unsigned short* __restrict__ Ca, unsigned short* __restrict__ Cb, int M) {
    // bijective XCD swizzle (m204); virtual order x-major, by fastest
    int nwg = gridDim.x;
    int q8 = nwg >> 3, r8 = nwg & 7;
    int b = blockIdx.x;
    int xcd = b & 7, rank = b >> 3;
    int v = (xcd < r8 ? xcd * (q8 + 1) : r8 * (q8 + 1) + (xcd - r8) * q8) + rank;
    int bx = v >> 1;
    int by = v & 1;

    const unsigned short* W0 = Wt;
    const unsigned short* W1 = Wt + 65536;

    __shared__ unsigned short As[2][128 * LDE];
    __shared__ unsigned short B0s[2][128 * LDE];
    __shared__ unsigned short B1s[2][128 * LDE];

    int m0 = bx * 128, n0 = by * 128;
    int tid = threadIdx.x;
    int lane = tid & 63, wid = tid >> 6;
    int wm = wid & 1, wn = wid >> 1;
    int q = lane >> 4, l15 = lane & 15;

    int lr = lane >> 2;
    int lc = (lane & 3) * 8;
    int Mm1 = M - 1;
    int ra0 = m0 + wid * 32 + lr;      if (ra0 > Mm1) ra0 = Mm1;
    int ra1 = m0 + wid * 32 + 16 + lr; if (ra1 > Mm1) ra1 = Mm1;
    const unsigned short* pa0 = A  + (size_t)ra0 * 256 + lc;
    const unsigned short* pa1 = A  + (size_t)ra1 * 256 + lc;
    size_t woff0 = (size_t)(n0 + wid * 32 + lr) * 256 + lc;
    size_t woff1 = (size_t)(n0 + wid * 32 + 16 + lr) * 256 + lc;
    const unsigned short* pb0 = W0 + woff0;
    const unsigned short* pb1 = W0 + woff1;
    const unsigned short* pc0 = W1 + woff0;
    const unsigned short* pc1 = W1 + woff1;

    f32x4 acc0[4][4], acc1[4][4];
#pragma unroll
    for (int i = 0; i < 4; ++i)
#pragma unroll
        for (int j = 0; j < 4; ++j) {
            acc0[i][j] = (f32x4){0.f, 0.f, 0.f, 0.f};
            acc1[i][j] = (f32x4){0.f, 0.f, 0.f, 0.f};
        }

#define STAGE(bf, kb) do {                                    \
        int koff = (kb) * 32;                                 \
        gload16(pa0 + koff, &As[bf][(wid * 32) * LDE]);       \
        gload16(pa1 + koff, &As[bf][(wid * 32 + 16) * LDE]);  \
        gload16(pb0 + koff, &B0s[bf][(wid * 32) * LDE]);      \
        gload16(pb1 + koff, &B0s[bf][(wid * 32 + 16) * LDE]); \
        gload16(pc0 + koff, &B1s[bf][(wid * 32) * LDE]);      \
        gload16(pc1 + koff, &B1s[bf][(wid * 32 + 16) * LDE]); \
    } while (0)

    STAGE(0, 0);
    __syncthreads();

#pragma unroll
    for (int kb = 0; kb < 8; ++kb) {
        int cur = kb & 1;
        if (kb < 7) STAGE(cur ^ 1, kb + 1);

        f16x8 af[4], bf0[4], bf1[4];
#pragma unroll
        for (int f = 0; f < 4; ++f)
            af[f] = *(const f16x8*)&As[cur][(wm * 64 + f * 16 + l15) * LDE + q * 8];
#pragma unroll
        for (int f = 0; f < 4; ++f)
            bf0[f] = *(const f16x8*)&B0s[cur][(wn * 64 + f * 16 + l15) * LDE + q * 8];
#pragma unroll
        for (int f = 0; f < 4; ++f)
            bf1[f] = *(const f16x8*)&B1s[cur][(wn * 64 + f * 16 + l15) * LDE + q * 8];
#pragma unroll
        for (int i = 0; i < 4; ++i)
#pragma unroll
            for (int j = 0; j < 4; ++j) {
                acc0[i][j] = __builtin_amdgcn_mfma_f32_16x16x32_f16(af[i], bf0[j], acc0[i][j], 0, 0, 0);
                acc1[i][j] = __builtin_amdgcn_mfma_f32_16x16x32_f16(af[i], bf1[j], acc1[i][j], 0, 0, 0);
            }

        __syncthreads();
    }
#undef STAGE

    // epilogue: j innermost so the 4x32B segments of each row's 128B span merge in L2
    float bc0[4], bc1[4];
#pragma unroll
    for (int j = 0; j < 4; ++j) {
        int gcol = n0 + wn * 64 + j * 16 + l15;
        bc0[j] = ba[gcol];
        bc1[j] = bb[gcol];
    }
#pragma unroll
    for (int i = 0; i < 4; ++i) {
        int row = m0 + wm * 64 + i * 16 + q * 4;
#pragma unroll
        for (int rr = 0; rr < 4; ++rr) {
            int grow = row + rr;
            if (grow < M) {
#pragma unroll
                for (int j = 0; j < 4; ++j) {
                    int gcol = n0 + wn * 64 + j * 16 + l15;
                    Ca[(size_t)grow * 256 + gcol] = f2h(acc0[i][j][rr] + bc0[j]);
                }
#pragma unroll
                for (int j = 0; j < 4; ++j) {
                    int gcol = n0 + wn * 64 + j * 16 + l15;
                    Cb[(size_t)grow * 256 + gcol] = f2h(acc1[i][j][rr] + bc1[j]);
                }
            }
        }
    }
}

extern "C" void kernel_launch(void* const* d_in, const int* in_sizes, int n_in,
                              void* d_out, int out_size, void* d_ws, size_t ws_size,
                              hipStream_t stream) {
    const float* x    = (const float*)d_in[0];
    const int*   ei   = (const int*)d_in[1];
    const float* Wl1  = (const float*)d_in[2];
    const float* bl1  = (const float*)d_in[3];
    const float* Wr1  = (const float*)d_in[4];
    const float* br1  = (const float*)d_in[5];
    const float* att1 = (const float*)d_in[6];
    const float* bias1= (const float*)d_in[7];
    const float* Wl2  = (const float*)d_in[8];
    const float* bl2  = (const float*)d_in[9];
    const float* Wr2  = (const float*)d_in[10];
    const float* br2  = (const float*)d_in[11];
    const float* att2 = (const float*)d_in[12];
    const float* bias2= (const float*)d_in[13];

    int n = in_sizes[0] / 20;
    int e = in_sizes[1] / 2;
    float* out = (float*)d_out;
    size_t nch = (size_t)n * CH;

    unsigned short* buf0 = (unsigned short*)d_ws;
    unsigned short* buf1 = buf0 + nch;
    unsigned short* hbuf = buf1 + nch;
    unsigned short* wt2  = hbuf + nch;
    int* deg    = (int*)(wt2 + 2 * 65536);
    int* rowptr = deg + n;
    int* cursor = rowptr + n + 1;
    int* bsums  = cursor + n;
    int* csr    = bsums + 64;

    hipMemsetAsync(deg, 0, (size_t)n * sizeof(int), stream);

    gemm1_kernel<<<(n + 63) / 64, 256, 0, stream>>>(x, Wl1, bl1, Wr1, br1, buf0, buf1, n);

    count_deg<<<(e + 255) / 256, 256, 0, stream>>>(ei, deg, e);
    int nb = (n + SCAN_BLOCK - 1) / SCAN_BLOCK;
    scan_block_k<<<nb, SCAN_BLOCK, 0, stream>>>(deg, rowptr, bsums, n);
    scan_tops_k<<<1, 64, 0, stream>>>(bsums, nb);
    scan_fix_k<<<nb, SCAN_BLOCK, 0, stream>>>(rowptr, cursor, deg, bsums, n);
    scatter_k<<<(e + 255) / 256, 256, 0, stream>>>(ei, cursor, csr, e);

    wconv<<<512, 256, 0, stream>>>(Wl2, Wr2, wt2);

    fused_gat1<<<(n + 3) / 4, 256, 0, stream>>>(buf0, buf1, rowptr, csr, att1, bias1, hbuf, n);

    int nxb = (n + 127) / 128;
    gemm_mfma<<<nxb * 2, 256, 0, stream>>>(hbuf, wt2, bl2, br2, buf0, buf1, n);

    fused_gat2<<<(n + 3) / 4, 256, 0, stream>>>(buf0, buf1, rowptr, csr, att2, bias2, out, n);
}

// Round 16
// 282.946 us; speedup vs baseline: 1.0149x; 1.0149x over previous
//
#include <hip/hip_runtime.h>
#include <math.h>

#define CH 256
#define SCAN_BLOCK 1024
#define LOG2E 1.44269504088896f

typedef _Float16 h2 __attribute__((ext_vector_type(2)));
typedef _Float16 h4 __attribute__((ext_vector_type(4)));
typedef _Float16 f16x8 __attribute__((ext_vector_type(8)));
typedef float f32x4 __attribute__((ext_vector_type(4)));

__device__ __forceinline__ float elu(float v)   { return v > 0.f ? v : __expf(v) - 1.f; }

__device__ __forceinline__ unsigned short f2h(float f) {
    union { _Float16 h; unsigned short u; } c;
    c.h = (_Float16)f;
    return c.u;
}

// packed-f16 edge logit: dot(att, lrelu(r + xr)) over this lane's 4 channels
__device__ __forceinline__ float edge_logit(h4 r, h2 xrlo, h2 xrhi, h2 alo, h2 ahi) {
    const h2 k = {(_Float16)0.2f, (_Float16)0.2f};
    h2 rlo = {r.x, r.y}, rhi = {r.z, r.w};
    h2 slo = rlo + xrlo;
    h2 shi = rhi + xrhi;
    slo = __builtin_elementwise_max(slo, slo * k);   // v_pk_max_f16 (lrelu)
    shi = __builtin_elementwise_max(shi, shi * k);
    float p = __builtin_amdgcn_fdot2(slo, alo, 0.f, false);   // v_dot2_f32_f16
    return __builtin_amdgcn_fdot2(shi, ahi, p, false);
}

// DPP butterfly add steps (VALU cross-lane, no DS pipe)
template<int C>
__device__ __forceinline__ float dppadd(float v) {
    int t = __builtin_amdgcn_update_dpp(0, __float_as_int(v), C, 0xf, 0xf, true);
    return v + __int_as_float(t);
}
// reduce within each 16-lane group: xor1,xor2 (quad_perm), xor4 (half_mirror), xor8 (mirror)
__device__ __forceinline__ float red16(float p) {
    p = dppadd<0xB1>(p);    // quad_perm [1,0,3,2]
    p = dppadd<0x4E>(p);    // quad_perm [2,3,0,1]
    p = dppadd<0x141>(p);   // row_half_mirror
    p = dppadd<0x140>(p);   // row_mirror
    return p;
}
// full 64-lane reduce: DPP within 16, then cross-row via shuffle (verified R6 structure)
__device__ __forceinline__ float red64(float p) {
    p = red16(p);
    p += __shfl_xor(p, 16);
    p += __shfl_xor(p, 32);
    return p;
}

// async global->LDS, 16B per lane, wave-uniform LDS base (dest = base + lane*16)
typedef const __attribute__((address_space(1))) unsigned int* gas_p;
typedef __attribute__((address_space(3))) unsigned int* las_p;
__device__ __forceinline__ void gload16(const unsigned short* g, unsigned short* l) {
    __builtin_amdgcn_global_load_lds((gas_p)g, (las_p)l, 16, 0, 0);
}

// ---------------- GEMM1: x (n x 20) @ W (20 x 256) + b -> f16 xl, xr ----------------
__global__ __launch_bounds__(256) void gemm1_kernel(const float* __restrict__ x,
                             const float* __restrict__ Wl, const float* __restrict__ bl,
                             const float* __restrict__ Wr, const float* __restrict__ br,
                             unsigned short* __restrict__ xl, unsigned short* __restrict__ xr, int n) {
    __shared__ float xs[64][20];
    int n0 = blockIdx.x * 64;
    int tid = threadIdx.x;
    for (int i = tid; i < 64 * 20; i += 256) {
        int m = i / 20, k = i % 20;
        int row = n0 + m;
        xs[m][k] = (row < n) ? x[(size_t)row * 20 + k] : 0.f;
    }
    int c = tid;
    float wl[20], wr[20];
#pragma unroll
    for (int k = 0; k < 20; ++k) { wl[k] = Wl[k * 256 + c]; wr[k] = Wr[k * 256 + c]; }
    float blv = bl[c], brv = br[c];
    __syncthreads();
#pragma unroll 1
    for (int g = 0; g < 8; ++g) {
        int base = g * 8;
        float al[8], ar[8];
#pragma unroll
        for (int m = 0; m < 8; ++m) { al[m] = blv; ar[m] = brv; }
#pragma unroll
        for (int k = 0; k < 20; ++k) {
            float wlv = wl[k], wrv = wr[k];
#pragma unroll
            for (int m = 0; m < 8; ++m) {
                float xv = xs[base + m][k];
                al[m] += xv * wlv;
                ar[m] += xv * wrv;
            }
        }
#pragma unroll
        for (int m = 0; m < 8; ++m) {
            int row = n0 + base + m;
            if (row < n) {
                xl[(size_t)row * 256 + c] = f2h(al[m]);
                xr[(size_t)row * 256 + c] = f2h(ar[m]);
            }
        }
    }
}

// ---------------- CSR build ----------------
__global__ void count_deg(const int* __restrict__ ei, int* __restrict__ deg, int e) {
    int t = blockIdx.x * blockDim.x + threadIdx.x;
    if (t < e) atomicAdd(&deg[ei[e + t]], 1);
}

__global__ void scan_block_k(const int* __restrict__ deg, int* __restrict__ rowptr,
                             int* __restrict__ bsums, int n) {
    __shared__ int wsum[16];
    __shared__ int woff[17];
    int tid = threadIdx.x;
    int gi = blockIdx.x * SCAN_BLOCK + tid;
    int lane = tid & 63, wid = tid >> 6;
    int v = (gi < n) ? deg[gi] : 0;
    int incl = v;
#pragma unroll
    for (int d = 1; d < 64; d <<= 1) {
        int t = __shfl_up(incl, d, 64);
        if (lane >= d) incl += t;
    }
    if (lane == 63) wsum[wid] = incl;
    __syncthreads();
    if (tid < 16) {
        int s = wsum[tid];
#pragma unroll
        for (int d = 1; d < 16; d <<= 1) {
            int t = __shfl_up(s, d, 64);
            if (tid >= d) s += t;
        }
        woff[tid + 1] = s;
        if (tid == 0) woff[0] = 0;
    }
    __syncthreads();
    incl += woff[wid];
    if (gi < n) rowptr[gi + 1] = incl;
    if (tid == 0) bsums[blockIdx.x] = woff[16];
}

__global__ void scan_tops_k(int* bsums, int nb) {
    int tid = threadIdx.x;
    int v = (tid < nb) ? bsums[tid] : 0;
    int incl = v;
#pragma unroll
    for (int d = 1; d < 64; d <<= 1) {
        int t = __shfl_up(incl, d, 64);
        if (tid >= d) incl += t;
    }
    if (tid < nb) bsums[tid] = incl - v;
}

__global__ void scan_fix_k(int* __restrict__ rowptr, int* __restrict__ cursor,
                           const int* __restrict__ deg, const int* __restrict__ bsums, int n) {
    int gi = blockIdx.x * SCAN_BLOCK + threadIdx.x;
    if (gi >= n) return;
    int off = bsums[blockIdx.x];
    int incl = rowptr[gi + 1] + off;
    rowptr[gi + 1] = incl;
    cursor[gi] = incl - deg[gi];
    if (gi == 0) rowptr[0] = 0;
}

__global__ void scatter_k(const int* __restrict__ ei, int* __restrict__ cursor,
                          int* __restrict__ csr, int e) {
    int t = blockIdx.x * blockDim.x + threadIdx.x;
    if (t >= e) return;
    int s = ei[t], d = ei[e + t];
    int idx = atomicAdd(&cursor[d], 1);
    csr[idx] = s;
}

// ---- Fused GATv2 layer 1 (f16 in, f16 out): no-max softmax, depth-2 quad pipeline,
// ---- ONE wave per block (per-node resource recycling; no block-level straggler hold)
__global__ __launch_bounds__(64) void fused_gat1(
                           const unsigned short* __restrict__ xl, const unsigned short* __restrict__ xr,
                           const int* __restrict__ rowptr, const int* __restrict__ csr,
                           const float* __restrict__ att, const float* __restrict__ bias,
                           unsigned short* __restrict__ hout, int n) {
    int lane = threadIdx.x & 63;
    int i = blockIdx.x;
    if (i >= n) return;
    h4 xr4 = ((const h4*)(xr + (size_t)i * CH))[lane];
    h2 xrlo = {xr4.x, xr4.y}, xrhi = {xr4.z, xr4.w};
    float4 a4 = ((const float4*)att)[lane];
    h2 alo = {(_Float16)(a4.x * LOG2E), (_Float16)(a4.y * LOG2E)};
    h2 ahi = {(_Float16)(a4.z * LOG2E), (_Float16)(a4.w * LOG2E)};
    h4 xli = ((const h4*)(xl + (size_t)i * CH))[lane];
    int beg = rowptr[i], end = rowptr[i + 1];
    int el = end - 1;
    // preload two quads (8 rows in flight) BEFORE the self-loop compute
    h4 A0, A1, A2, A3, B0, B1, B2, B3;
    int e0 = beg;
    if (e0 < end) {
        int s0 = csr[e0], s1 = csr[min(e0 + 1, el)], s2 = csr[min(e0 + 2, el)], s3 = csr[min(e0 + 3, el)];
        A0 = ((const h4*)(xl + (size_t)s0 * CH))[lane];
        A1 = ((const h4*)(xl + (size_t)s1 * CH))[lane];
        A2 = ((const h4*)(xl + (size_t)s2 * CH))[lane];
        A3 = ((const h4*)(xl + (size_t)s3 * CH))[lane];
        e0 += 4;
    }
    if (e0 < end) {
        int s0 = csr[e0], s1 = csr[min(e0 + 1, el)], s2 = csr[min(e0 + 2, el)], s3 = csr[min(e0 + 3, el)];
        B0 = ((const h4*)(xl + (size_t)s0 * CH))[lane];
        B1 = ((const h4*)(xl + (size_t)s1 * CH))[lane];
        B2 = ((const h4*)(xl + (size_t)s2 * CH))[lane];
        B3 = ((const h4*)(xl + (size_t)s3 * CH))[lane];
        e0 += 4;
    }
    // self-loop (overlaps with in-flight gathers)
    float ws = __builtin_exp2f(red16(edge_logit(xli, xrlo, xrhi, alo, ahi)));
    float l = ws;
    float4 acc = make_float4(ws * (float)xli.x, ws * (float)xli.y,
                             ws * (float)xli.z, ws * (float)xli.w);

#define GAT1_COMPUTE(Q0, Q1, Q2, Q3, eg)  do {                                   \
        int cnt = end - (eg);                                                    \
        float p0 = red16(edge_logit(Q0, xrlo, xrhi, alo, ahi));                  \
        float p1 = red16(edge_logit(Q1, xrlo, xrhi, alo, ahi));                  \
        float p2 = red16(edge_logit(Q2, xrlo, xrhi, alo, ahi));                  \
        float p3 = red16(edge_logit(Q3, xrlo, xrhi, alo, ahi));                  \
        if (cnt < 2) p1 = -INFINITY;                                             \
        if (cnt < 3) p2 = -INFINITY;                                             \
        if (cnt < 4) p3 = -INFINITY;                                             \
        float w0 = __builtin_exp2f(p0), w1 = __builtin_exp2f(p1);                \
        float w2 = __builtin_exp2f(p2), w3 = __builtin_exp2f(p3);                \
        l += (w0 + w1) + (w2 + w3);                                              \
        acc.x += w0*(float)Q0.x + w1*(float)Q1.x + w2*(float)Q2.x + w3*(float)Q3.x; \
        acc.y += w0*(float)Q0.y + w1*(float)Q1.y + w2*(float)Q2.y + w3*(float)Q3.y; \
        acc.z += w0*(float)Q0.z + w1*(float)Q1.z + w2*(float)Q2.z + w3*(float)Q3.z; \
        acc.w += w0*(float)Q0.w + w1*(float)Q1.w + w2*(float)Q2.w + w3*(float)Q3.w; \
    } while (0)

#define GAT_REFILL(Q0, Q1, Q2, Q3)  do {                                         \
        if (e0 < end) {                                                          \
            int s0 = csr[e0], s1 = csr[min(e0 + 1, el)];                         \
            int s2 = csr[min(e0 + 2, el)], s3 = csr[min(e0 + 3, el)];            \
            Q0 = ((const h4*)(xl + (size_t)s0 * CH))[lane];                      \
            Q1 = ((const h4*)(xl + (size_t)s1 * CH))[lane];                      \
            Q2 = ((const h4*)(xl + (size_t)s2 * CH))[lane];                      \
            Q3 = ((const h4*)(xl + (size_t)s3 * CH))[lane];                      \
            e0 += 4;                                                             \
        }                                                                        \
    } while (0)

    int e = beg;
    while (e < end) {
        GAT1_COMPUTE(A0, A1, A2, A3, e);
        e += 4;
        if (e >= end) break;
        GAT_REFILL(A0, A1, A2, A3);
        GAT1_COMPUTE(B0, B1, B2, B3, e);
        e += 4;
        if (e >= end) break;
        GAT_REFILL(B0, B1, B2, B3);
    }
#undef GAT1_COMPUTE

    float inv = 1.f / l;
    float4 b4 = ((const float4*)bias)[lane];
    h4 o;
    o.x = (_Float16)elu(acc.x * inv + b4.x);
    o.y = (_Float16)elu(acc.y * inv + b4.y);
    o.z = (_Float16)elu(acc.z * inv + b4.z);
    o.w = (_Float16)elu(acc.w * inv + b4.w);
    ((h4*)(hout + (size_t)i * CH))[lane] = o;
}

// ---- Fused GATv2 layer 2 (f16 in, fp32 out): same structure, 64-lane reduce, 1 wave/block ----
__global__ __launch_bounds__(64) void fused_gat2(
                           const unsigned short* __restrict__ xl, const unsigned short* __restrict__ xr,
                           const int* __restrict__ rowptr, const int* __restrict__ csr,
                           const float* __restrict__ att, const float* __restrict__ bias,
                           float* __restrict__ out, int n) {
    int lane = threadIdx.x & 63;
    int i = blockIdx.x;
    if (i >= n) return;
    h4 xr4 = ((const h4*)(xr + (size_t)i * CH))[lane];
    h2 xrlo = {xr4.x, xr4.y}, xrhi = {xr4.z, xr4.w};
    float4 a4 = ((const float4*)att)[lane];
    h2 alo = {(_Float16)(a4.x * LOG2E), (_Float16)(a4.y * LOG2E)};
    h2 ahi = {(_Float16)(a4.z * LOG2E), (_Float16)(a4.w * LOG2E)};
    h4 xli = ((const h4*)(xl + (size_t)i * CH))[lane];
    int beg = rowptr[i], end = rowptr[i + 1];
    int el = end - 1;
    h4 A0, A1, A2, A3, B0, B1, B2, B3;
    int e0 = beg;
    if (e0 < end) {
        int s0 = csr[e0], s1 = csr[min(e0 + 1, el)], s2 = csr[min(e0 + 2, el)], s3 = csr[min(e0 + 3, el)];
        A0 = ((const h4*)(xl + (size_t)s0 * CH))[lane];
        A1 = ((const h4*)(xl + (size_t)s1 * CH))[lane];
        A2 = ((const h4*)(xl + (size_t)s2 * CH))[lane];
        A3 = ((const h4*)(xl + (size_t)s3 * CH))[lane];
        e0 += 4;
    }
    if (e0 < end) {
        int s0 = csr[e0], s1 = csr[min(e0 + 1, el)], s2 = csr[min(e0 + 2, el)], s3 = csr[min(e0 + 3, el)];
        B0 = ((const h4*)(xl + (size_t)s0 * CH))[lane];
        B1 = ((const h4*)(xl + (size_t)s1 * CH))[lane];
        B2 = ((const h4*)(xl + (size_t)s2 * CH))[lane];
        B3 = ((const h4*)(xl + (size_t)s3 * CH))[lane];
        e0 += 4;
    }
    float ws = __builtin_exp2f(red64(edge_logit(xli, xrlo, xrhi, alo, ahi)));
    float l = ws;
    float4 acc = make_float4(ws * (float)xli.x, ws * (float)xli.y,
                             ws * (float)xli.z, ws * (float)xli.w);

#define GAT2_COMPUTE(Q0, Q1, Q2, Q3, eg)  do {                                   \
        int cnt = end - (eg);                                                    \
        float p0 = red64(edge_logit(Q0, xrlo, xrhi, alo, ahi));                  \
        float p1 = red64(edge_logit(Q1, xrlo, xrhi, alo, ahi));                  \
        float p2 = red64(edge_logit(Q2, xrlo, xrhi, alo, ahi));                  \
        float p3 = red64(edge_logit(Q3, xrlo, xrhi, alo, ahi));                  \
        if (cnt < 2) p1 = -INFINITY;                                             \
        if (cnt < 3) p2 = -INFINITY;                                             \
        if (cnt < 4) p3 = -INFINITY;                                             \
        float w0 = __builtin_exp2f(p0), w1 = __builtin_exp2f(p1);                \
        float w2 = __builtin_exp2f(p2), w3 = __builtin_exp2f(p3);                \
        l += (w0 + w1) + (w2 + w3);                                              \
        acc.x += w0*(float)Q0.x + w1*(float)Q1.x + w2*(float)Q2.x + w3*(float)Q3.x; \
        acc.y += w0*(float)Q0.y + w1*(float)Q1.y + w2*(float)Q2.y + w3*(float)Q3.y; \
        acc.z += w0*(float)Q0.z + w1*(float)Q1.z + w2*(float)Q2.z + w3*(float)Q3.z; \
        acc.w += w0*(float)Q0.w + w1*(float)Q1.w + w2*(float)Q2.w + w3*(float)Q3.w; \
    } while (0)

    int e = beg;
    while (e < end) {
        GAT2_COMPUTE(A0, A1, A2, A3, e);
        e += 4;
        if (e >= end) break;
        GAT_REFILL(A0, A1, A2, A3);
        GAT2_COMPUTE(B0, B1, B2, B3, e);
        e += 4;
        if (e >= end) break;
        GAT_REFILL(B0, B1, B2, B3);
    }
#undef GAT2_COMPUTE
#undef GAT_REFILL

    float inv = 1.f / l;
    float4 b4 = ((const float4*)bias)[lane];
    float4 o;
    o.x = acc.x * inv + b4.x;
    o.y = acc.y * inv + b4.y;
    o.z = acc.z * inv + b4.z;
    o.w = acc.w * inv + b4.w;
    ((float4*)(out + (size_t)i * CH))[lane] = o;
}

// ---------------- transpose+convert layer2 weights: Wt[z][n][k] f16 ----------------
__global__ void wconv(const float* __restrict__ Wl2, const float* __restrict__ Wr2,
                      unsigned short* __restrict__ Wt) {
    int t = blockIdx.x * 256 + threadIdx.x;
    int z = t >> 16;
    int idx = t & 65535;
    int k = idx >> 8, nn = idx & 255;
    const float* W = z ? Wr2 : Wl2;
    Wt[z * 65536 + nn * 256 + k] = f2h(W[k * 256 + nn]);
}

// ---------------- GEMM2 MFMA: h (M x 256 f16) @ {Wl2,Wr2}^T + b, BOTH z per block ----
#define LDE 32
__global__ __launch_bounds__(256) void gemm_mfma(
        const unsigned short* __restrict__ A,
        const unsigned short* __restrict__ Wt,
        const float* __restrict__ ba, const float* __restrict__ bb,
        unsigned short* __restrict__ Ca, unsigned short* __restrict__ Cb, int M) {
    // bijective XCD swizzle (m204); virtual order x-major, by fastest
    int nwg = gridDim.x;
    int q8 = nwg >> 3, r8 = nwg & 7;
    int b = blockIdx.x;
    int xcd = b & 7, rank = b >> 3;
    int v = (xcd < r8 ? xcd * (q8 + 1) : r8 * (q8 + 1) + (xcd - r8) * q8) + rank;
    int bx = v >> 1;
    int by = v & 1;

    const unsigned short* W0 = Wt;
    const unsigned short* W1 = Wt + 65536;

    __shared__ unsigned short As[2][128 * LDE];
    __shared__ unsigned short B0s[2][128 * LDE];
    __shared__ unsigned short B1s[2][128 * LDE];

    int m0 = bx * 128, n0 = by * 128;
    int tid = threadIdx.x;
    int lane = tid & 63, wid = tid >> 6;
    int wm = wid & 1, wn = wid >> 1;
    int q = lane >> 4, l15 = lane & 15;

    int lr = lane >> 2;
    int lc = (lane & 3) * 8;
    int Mm1 = M - 1;
    int ra0 = m0 + wid * 32 + lr;      if (ra0 > Mm1) ra0 = Mm1;
    int ra1 = m0 + wid * 32 + 16 + lr; if (ra1 > Mm1) ra1 = Mm1;
    const unsigned short* pa0 = A  + (size_t)ra0 * 256 + lc;
    const unsigned short* pa1 = A  + (size_t)ra1 * 256 + lc;
    size_t woff0 = (size_t)(n0 + wid * 32 + lr) * 256 + lc;
    size_t woff1 = (size_t)(n0 + wid * 32 + 16 + lr) * 256 + lc;
    const unsigned short* pb0 = W0 + woff0;
    const unsigned short* pb1 = W0 + woff1;
    const unsigned short* pc0 = W1 + woff0;
    const unsigned short* pc1 = W1 + woff1;

    f32x4 acc0[4][4], acc1[4][4];
#pragma unroll
    for (int i = 0; i < 4; ++i)
#pragma unroll
        for (int j = 0; j < 4; ++j) {
            acc0[i][j] = (f32x4){0.f, 0.f, 0.f, 0.f};
            acc1[i][j] = (f32x4){0.f, 0.f, 0.f, 0.f};
        }

#define STAGE(bf, kb) do {                                    \
        int koff = (kb) * 32;                                 \
        gload16(pa0 + koff, &As[bf][(wid * 32) * LDE]);       \
        gload16(pa1 + koff, &As[bf][(wid * 32 + 16) * LDE]);  \
        gload16(pb0 + koff, &B0s[bf][(wid * 32) * LDE]);      \
        gload16(pb1 + koff, &B0s[bf][(wid * 32 + 16) * LDE]); \
        gload16(pc0 + koff, &B1s[bf][(wid * 32) * LDE]);      \
        gload16(pc1 + koff, &B1s[bf][(wid * 32 + 16) * LDE]); \
    } while (0)

    STAGE(0, 0);
    __syncthreads();

#pragma unroll
    for (int kb = 0; kb < 8; ++kb) {
        int cur = kb & 1;
        if (kb < 7) STAGE(cur ^ 1, kb + 1);

        f16x8 af[4], bf0[4], bf1[4];
#pragma unroll
        for (int f = 0; f < 4; ++f)
            af[f] = *(const f16x8*)&As[cur][(wm * 64 + f * 16 + l15) * LDE + q * 8];
#pragma unroll
        for (int f = 0; f < 4; ++f)
            bf0[f] = *(const f16x8*)&B0s[cur][(wn * 64 + f * 16 + l15) * LDE + q * 8];
#pragma unroll
        for (int f = 0; f < 4; ++f)
            bf1[f] = *(const f16x8*)&B1s[cur][(wn * 64 + f * 16 + l15) * LDE + q * 8];
#pragma unroll
        for (int i = 0; i < 4; ++i)
#pragma unroll
            for (int j = 0; j < 4; ++j) {
                acc0[i][j] = __builtin_amdgcn_mfma_f32_16x16x32_f16(af[i], bf0[j], acc0[i][j], 0, 0, 0);
                acc1[i][j] = __builtin_amdgcn_mfma_f32_16x16x32_f16(af[i], bf1[j], acc1[i][j], 0, 0, 0);
            }

        __syncthreads();
    }
#undef STAGE

    // epilogue: j innermost so the 4x32B segments of each row's 128B span merge in L2
    float bc0[4], bc1[4];
#pragma unroll
    for (int j = 0; j < 4; ++j) {
        int gcol = n0 + wn * 64 + j * 16 + l15;
        bc0[j] = ba[gcol];
        bc1[j] = bb[gcol];
    }
#pragma unroll
    for (int i = 0; i < 4; ++i) {
        int row = m0 + wm * 64 + i * 16 + q * 4;
#pragma unroll
        for (int rr = 0; rr < 4; ++rr) {
            int grow = row + rr;
            if (grow < M) {
#pragma unroll
                for (int j = 0; j < 4; ++j) {
                    int gcol = n0 + wn * 64 + j * 16 + l15;
                    Ca[(size_t)grow * 256 + gcol] = f2h(acc0[i][j][rr] + bc0[j]);
                }
#pragma unroll
                for (int j = 0; j < 4; ++j) {
                    int gcol = n0 + wn * 64 + j * 16 + l15;
                    Cb[(size_t)grow * 256 + gcol] = f2h(acc1[i][j][rr] + bc1[j]);
                }
            }
        }
    }
}

extern "C" void kernel_launch(void* const* d_in, const int* in_sizes, int n_in,
                              void* d_out, int out_size, void* d_ws, size_t ws_size,
                              hipStream_t stream) {
    const float* x    = (const float*)d_in[0];
    const int*   ei   = (const int*)d_in[1];
    const float* Wl1  = (const float*)d_in[2];
    const float* bl1  = (const float*)d_in[3];
    const float* Wr1  = (const float*)d_in[4];
    const float* br1  = (const float*)d_in[5];
    const float* att1 = (const float*)d_in[6];
    const float* bias1= (const float*)d_in[7];
    const float* Wl2  = (const float*)d_in[8];
    const float* bl2  = (const float*)d_in[9];
    const float* Wr2  = (const float*)d_in[10];
    const float* br2  = (const float*)d_in[11];
    const float* att2 = (const float*)d_in[12];
    const float* bias2= (const float*)d_in[13];

    int n = in_sizes[0] / 20;
    int e = in_sizes[1] / 2;
    float* out = (float*)d_out;
    size_t nch = (size_t)n * CH;

    unsigned short* buf0 = (unsigned short*)d_ws;
    unsigned short* buf1 = buf0 + nch;
    unsigned short* hbuf = buf1 + nch;
    unsigned short* wt2  = hbuf + nch;
    int* deg    = (int*)(wt2 + 2 * 65536);
    int* rowptr = deg + n;
    int* cursor = rowptr + n + 1;
    int* bsums  = cursor + n;
    int* csr    = bsums + 64;

    hipMemsetAsync(deg, 0, (size_t)n * sizeof(int), stream);

    gemm1_kernel<<<(n + 63) / 64, 256, 0, stream>>>(x, Wl1, bl1, Wr1, br1, buf0, buf1, n);

    count_deg<<<(e + 255) / 256, 256, 0, stream>>>(ei, deg, e);
    int nb = (n + SCAN_BLOCK - 1) / SCAN_BLOCK;
    scan_block_k<<<nb, SCAN_BLOCK, 0, stream>>>(deg, rowptr, bsums, n);
    scan_tops_k<<<1, 64, 0, stream>>>(bsums, nb);
    scan_fix_k<<<nb, SCAN_BLOCK, 0, stream>>>(rowptr, cursor, deg, bsums, n);
    scatter_k<<<(e + 255) / 256, 256, 0, stream>>>(ei, cursor, csr, e);

    wconv<<<512, 256, 0, stream>>>(Wl2, Wr2, wt2);

    fused_gat1<<<n, 64, 0, stream>>>(buf0, buf1, rowptr, csr, att1, bias1, hbuf, n);

    int nxb = (n + 127) / 128;
    gemm_mfma<<<nxb * 2, 256, 0, stream>>>(hbuf, wt2, bl2, br2, buf0, buf1, n);

    fused_gat2<<<n, 64, 0, stream>>>(buf0, buf1, rowptr, csr, att2, bias2, out, n);
}